// Round 4
// baseline (298.301 us; speedup 1.0000x reference)
//
#include <hip/hip_runtime.h>
#include <stdint.h>

// ---------------------------------------------------------------------------
// pcnn via MFMA, round 4: latency-bound fixes.
//  - Separate __shared__ Ha/Hb (compile-time parity) -> provable no-alias,
//    cross-pixel software pipelining (was: one lds[] + runtime offset = fence).
//  - Branch-free 9 taps: invalid neighbors redirect to a zeroed dummy slab
//    (uniform s_cselect base), MFMA adds zeros. Straight-line p-loop body.
//  - LDS 57.3 KB -> 53.4 KB (drop IN3; colors recomputed from global in
//    epilogue; logits/softmax overlay dead Ha) -> 3 blocks/CU, 12 waves.
// Mapping per conv layer, per output pixel p:
//    out[o, b] += sum_t W_t[25x25] @ H[c, nb(p,t), b]
// mfma_f32_16x16x32_bf16: N=16 patches, K=32 (25ch zero-pad), M=2x16 tiles.
// ---------------------------------------------------------------------------

typedef short bf16x8 __attribute__((ext_vector_type(8)));
typedef float f32x4  __attribute__((ext_vector_type(4)));

// d_ws layout: bf16 section (u16 elems):
//   WALL [7][9][32o][32c] @ 0      (64512)   layer0 + 6 mid, zero-padded
//   WL   [9][16o][32c]    @ 64512  (4608)    last layer (6 out ch used)
// f32 section @ byte 138240:
//   BALL [7][32] @0, BL [32] @224, WPOST [18][3][25] @256, BPOST [18] @1606
#define WSB_WL    64512
#define WSB_U16   69120
#define WSF_BYTE  138240
#define WSF_BALL  0
#define WSF_BL    224
#define WSF_WPOST 256
#define WSF_BPOST 1606
#define WSF_N     1624

__device__ __forceinline__ float b2f(unsigned short u) {
  union { unsigned int u; float f; } v; v.u = ((unsigned int)u) << 16; return v.f;
}
__device__ __forceinline__ unsigned short f2b(float f) {
  union { float f; unsigned int u; } v; v.f = f;
  unsigned int r = v.u + 0x7fffu + ((v.u >> 16) & 1u);  // RNE
  return (unsigned short)(r >> 16);
}
__device__ __forceinline__ bool sniff_is_f32(const void* w0raw) {
  const unsigned short* q = (const unsigned short*)w0raw;
  int hits = 0;
  #pragma unroll
  for (int i = 0; i < 64; ++i) {
    unsigned int e = (q[i] >> 7) & 0xFFu;
    if (e >= 130u) ++hits;
  }
  return hits > 0;
}
__device__ __forceinline__ float ldw(const void* p, long idx, bool f32) {
  return f32 ? ((const float*)p)[idx] : b2f(((const unsigned short*)p)[idx]);
}

// ---------------- weight pre-pack (unchanged from R3) ----------------------
__global__ void prep_weights(const void* __restrict__ w0,
                             const void* __restrict__ b0,
                             const void* __restrict__ wm,
                             const void* __restrict__ bm,
                             const void* __restrict__ wl,
                             const void* __restrict__ bl,
                             const void* __restrict__ wp,
                             const void* __restrict__ bp,
                             unsigned short* __restrict__ wsb,
                             float* __restrict__ wsf) {
  const bool f32 = sniff_is_f32(w0);
  int e = blockIdx.x * blockDim.x + threadIdx.x;
  if (e < WSB_WL) {                       // WALL[l][t][o][c]
    int l = e / 9216, r = e % 9216, t = r / 1024, r2 = r % 1024;
    int o = r2 / 32, c = r2 % 32;
    float v = 0.f;
    if (l == 0) { if (o < 25 && c < 8)  v = ldw(w0, (o * 8 + c) * 9 + t, f32); }
    else        { if (o < 25 && c < 25) v = ldw(wm, (((l - 1) * 25 + o) * 25 + c) * 9 + t, f32); }
    wsb[e] = f2b(v);
  } else if (e < WSB_U16) {               // WL[t][o][c]
    int q = e - WSB_WL;
    int t = q / 512, r = q % 512, o = r / 32, c = r % 32;
    float v = 0.f;
    if (o < 6 && c < 25) v = ldw(wl, (o * 25 + c) * 9 + t, f32);
    wsb[e] = f2b(v);
  } else {
    int q = e - WSB_U16;
    if (q < 224) {                        // BALL[l][32]
      int l = q / 32, o = q % 32;
      float v = 0.f;
      if (o < 25) v = (l == 0) ? ldw(b0, o, f32) : ldw(bm, (l - 1) * 25 + o, f32);
      wsf[WSF_BALL + q] = v;
    } else if (q < 256) {
      int o = q - 224;
      wsf[WSF_BL + o] = (o < 6) ? ldw(bl, o, f32) : 0.f;
    } else if (q < 256 + 1350) {
      wsf[WSF_WPOST + (q - 256)] = ldw(wp, q - 256, f32);
    } else if (q < 256 + 1350 + 18) {
      wsf[WSF_BPOST + (q - 1606)] = ldw(bp, q - 1606, f32);
    }
  }
}

// ---------------- one conv layer (25->25, relu) ----------------------------
// hin/hout point at DISTINCT __shared__ arrays -> no-alias -> pipelining.
// Branch-free: all 9 taps run; invalid neighbors read the zero dummy slab.
__device__ __forceinline__ void conv_layer(
    const short* __restrict__ hin, short* __restrict__ hout,
    const short* __restrict__ dzero,
    const unsigned short* __restrict__ WA, const float* __restrict__ biasv,
    int p0, int p1, int col, int quad) {
  bf16x8 af0[9], af1[9];
  #pragma unroll
  for (int t = 0; t < 9; ++t) {
    af0[t] = *(const bf16x8*)(WA + (t * 32 + col) * 32 + quad * 8);
    af1[t] = *(const bf16x8*)(WA + (t * 32 + 16 + col) * 32 + quad * 8);
  }
  const f32x4 bias0 = *(const f32x4*)(biasv + quad * 4);
  const f32x4 bias1 = *(const f32x4*)(biasv + 16 + quad * 4);
  const int loffs = col * 32 + quad * 8;  // in shorts

  for (int p = p0; p < p1; ++p) {
    const int py = p / 5, px = p % 5;
    const short* base[9];
    #pragma unroll
    for (int dy = -1; dy <= 1; ++dy)
      #pragma unroll
      for (int dx = -1; dx <= 1; ++dx) {
        const int ny = py + dy, nx = px + dx;
        const bool v = ((unsigned)ny < 5u) & ((unsigned)nx < 5u);
        base[(dy + 1) * 3 + (dx + 1)] = v ? hin + (ny * 5 + nx) * 512 : dzero;
      }
    f32x4 a0 = bias0, a1 = bias1;
    #pragma unroll
    for (int t = 0; t < 9; ++t) {
      bf16x8 bf = *(const bf16x8*)(base[t] + loffs);
      a0 = __builtin_amdgcn_mfma_f32_16x16x32_bf16(af0[t], bf, a0, 0, 0, 0);
      a1 = __builtin_amdgcn_mfma_f32_16x16x32_bf16(af1[t], bf, a1, 0, 0, 0);
    }
    // relu + cvt + store (rows quad*4..+3; tile0 -> ch, tile1 -> ch+16)
    short* op = hout + p * 512 + col * 32;
    uint2 s0;
    s0.x = (unsigned int)f2b(fmaxf(a0[0], 0.f)) | ((unsigned int)f2b(fmaxf(a0[1], 0.f)) << 16);
    s0.y = (unsigned int)f2b(fmaxf(a0[2], 0.f)) | ((unsigned int)f2b(fmaxf(a0[3], 0.f)) << 16);
    *(uint2*)(op + quad * 4) = s0;
    if (quad < 2) {
      uint2 s1;
      s1.x = (unsigned int)f2b(fmaxf(a1[0], 0.f)) | ((unsigned int)f2b(fmaxf(a1[1], 0.f)) << 16);
      s1.y = (unsigned int)f2b(fmaxf(a1[2], 0.f)) | ((unsigned int)f2b(fmaxf(a1[3], 0.f)) << 16);
      *(uint2*)(op + 16 + quad * 4) = s1;
    } else if (quad == 2) {  // ch 24
      *(unsigned short*)(op + 24) = f2b(fmaxf(a1[0], 0.f));
    }
  }
}

// ---------------- main kernel ----------------------------------------------
__global__ __launch_bounds__(256, 3) void pcnn_mfma(
    const void* __restrict__ inp,
    const void* __restrict__ w0raw,
    const unsigned short* __restrict__ wsb,
    const float* __restrict__ wsf,
    void* __restrict__ out) {
  __shared__ __align__(16) short Ha[25 * 512];   // [25pix][16b][32ch] 25600 B
  __shared__ __align__(16) short Hb[25 * 512];   // 25600 B
  __shared__ __align__(16) short Hz[512];        // zero dummy slab 1024 B
  __shared__ float colb[16 * 18];                // colors 1152 B
  // overlays on dead Ha after the mid layers:
  float* logits = (float*)Ha;                    // [25p][16b][8] f32 12800 B
  float* smb    = (float*)(Ha + 6400);           // [25p][16b][6] f32  9600 B

  const bool f32m = sniff_is_f32(w0raw);
  const int tid  = threadIdx.x;
  const int lane = tid & 63;
  const int wv   = tid >> 6;
  const int col  = lane & 15;            // MFMA n (patch) / m (out ch)
  const int quad = lane >> 4;            // MFMA k-block / row-block
  const int g    = blockIdx.x;           // group of 16 patches
  const int p0 = wv * 6, p1 = (wv == 3) ? 25 : p0 + 6;

  // zero Ha, Hb (ch 25..31 pad must stay 0), dummy slab
  for (int i = tid; i < 6400; i += 256) ((unsigned int*)Ha)[i] = 0u;
  for (int i = tid; i < 6400; i += 256) ((unsigned int*)Hb)[i] = 0u;
  if (tid < 256) { ((unsigned int*)Hz)[tid] = 0u; }
  __syncthreads();

  // stage input: [b][8c][25pix] -> Ha[pix][b][c]
  for (int e = tid; e < 3200; e += 256) {
    int b = e / 200, r = e % 200, c = r / 25, pix = r % 25;
    float v = ldw(inp, (long)g * 3200 + e, f32m);
    ((unsigned short*)Ha)[(pix * 16 + b) * 32 + c] = f2b(v);
  }
  __syncthreads();

  // ---- 7 relu conv layers, compile-time ping-pong Ha<->Hb ----
  conv_layer(Ha, Hb, Hz, wsb + 0 * 9216, wsf + WSF_BALL + 0 * 32, p0, p1, col, quad);
  __syncthreads();
  #pragma unroll
  for (int lp = 1; lp < 6; lp += 2) {
    conv_layer(Hb, Ha, Hz, wsb + lp * 9216, wsf + WSF_BALL + lp * 32, p0, p1, col, quad);
    __syncthreads();
    conv_layer(Ha, Hb, Hz, wsb + (lp + 1) * 9216, wsf + WSF_BALL + (lp + 1) * 32, p0, p1, col, quad);
    __syncthreads();
  }
  // final hidden is in Hb; Ha is dead -> overlay logits there.

  // ---- last layer: 25 -> 6 logits (no relu) ----
  {
    const unsigned short* WA = wsb + WSB_WL;
    bf16x8 afl[9];
    #pragma unroll
    for (int t = 0; t < 9; ++t)
      afl[t] = *(const bf16x8*)(WA + (t * 16 + col) * 32 + quad * 8);
    const f32x4 biasl = *(const f32x4*)(wsf + WSF_BL + quad * 4);
    const int loffs = col * 32 + quad * 8;

    for (int p = p0; p < p1; ++p) {
      const int py = p / 5, px = p % 5;
      const short* base[9];
      #pragma unroll
      for (int dy = -1; dy <= 1; ++dy)
        #pragma unroll
        for (int dx = -1; dx <= 1; ++dx) {
          const int ny = py + dy, nx = px + dx;
          const bool v = ((unsigned)ny < 5u) & ((unsigned)nx < 5u);
          base[(dy + 1) * 3 + (dx + 1)] = v ? Hb + (ny * 5 + nx) * 512 : Hz;
        }
      f32x4 a0 = biasl;
      #pragma unroll
      for (int t = 0; t < 9; ++t) {
        bf16x8 bf = *(const bf16x8*)(base[t] + loffs);
        a0 = __builtin_amdgcn_mfma_f32_16x16x32_bf16(afl[t], bf, a0, 0, 0, 0);
      }
      float* lp = logits + (p * 16 + col) * 8;
      if (quad == 0)      { *(f32x4*)lp = a0; }            // rows 0..3
      else if (quad == 1) { lp[4] = a0[0]; lp[5] = a0[1]; } // rows 4,5
    }
  }
  __syncthreads();

  // ---- epilogue: colors (postconv, re-read input from global) + softmax ----
  {
    const float* WP = wsf + WSF_WPOST;
    const float* BP = wsf + WSF_BPOST;
    for (int j = tid; j < 288; j += 256) {
      int b = j / 18, oc = j % 18;
      const long ib = (long)g * 3200 + b * 200;
      float s = BP[oc];
      #pragma unroll
      for (int ic = 0; ic < 3; ++ic) {
        #pragma unroll
        for (int pix = 0; pix < 25; ++pix)
          s = fmaf(WP[(oc * 3 + ic) * 25 + pix], ldw(inp, ib + ic * 25 + pix, f32m), s);
      }
      colb[b * 18 + oc] = s;
    }
    for (int j = tid; j < 400; j += 256) {
      const float* lp = logits + j * 8;
      float m = lp[0];
      #pragma unroll
      for (int k = 1; k < 6; ++k) m = fmaxf(m, lp[k]);
      float e[6], s = 0.f;
      #pragma unroll
      for (int k = 0; k < 6; ++k) { e[k] = __expf(lp[k] - m); s += e[k]; }
      const float inv = 1.f / s;
      #pragma unroll
      for (int k = 0; k < 6; ++k) smb[j * 6 + k] = e[k] * inv;
    }
  }
  __syncthreads();

  // ---- mix + store: out[b][c][p] = sum_w colors[b][c*6+w] * sm[p][b][w] ----
  for (int e = tid; e < 1200; e += 256) {
    int b = e / 75, r = e % 75, c = r / 25, p = r % 25;
    float v = 0.f;
    #pragma unroll
    for (int w = 0; w < 6; ++w)
      v = fmaf(colb[b * 18 + c * 6 + w], smb[(p * 16 + b) * 6 + w], v);
    const long oidx = (long)g * 1200 + e;
    if (f32m) ((float*)out)[oidx] = v;
    else      ((unsigned short*)out)[oidx] = f2b(v);
  }
}

extern "C" void kernel_launch(void* const* d_in, const int* in_sizes, int n_in,
                              void* d_out, int out_size, void* d_ws, size_t ws_size,
                              hipStream_t stream) {
  unsigned short* wsb = (unsigned short*)d_ws;
  float* wsf = (float*)((char*)d_ws + WSF_BYTE);
  const int B = in_sizes[0] / 200;  // 32768

  const int prep_n = WSB_U16 + WSF_N;
  prep_weights<<<(prep_n + 255) / 256, 256, 0, stream>>>(
      d_in[1], d_in[2], d_in[3], d_in[4], d_in[5], d_in[6], d_in[7], d_in[8],
      wsb, wsf);
  pcnn_mfma<<<B / 16, 256, 0, stream>>>(d_in[0], d_in[1], wsb, wsf, d_out);
}